// Round 12
// baseline (366.221 us; speedup 1.0000x reference)
//
#include <hip/hip_runtime.h>
#include <hip/hip_bf16.h>

// All external tensors are FLOAT32; bf16 is used only internally for MFMA.
typedef __bf16 bf16;
typedef __bf16 bfrag __attribute__((ext_vector_type(8)));   // 8 bf16 = 4 VGPRs (MFMA A/B)
typedef __bf16 bf16x2 __attribute__((ext_vector_type(2)));  // cvt_pk pair
typedef float f32x4 __attribute__((ext_vector_type(4)));    // 16x16 MFMA C/D
typedef float f32x16 __attribute__((ext_vector_type(16)));  // 32x32 MFMA C/D
typedef unsigned u32x2 __attribute__((ext_vector_type(2))); // permlane32_swap result

constexpr int Bc = 4, Sc = 2048, Hc = 16, ADc = 64, HIDc = 1024;
constexpr size_t QKV_ELEMS = (size_t)Bc * Hc * Sc * ADc;    // 8388608 (16 MB bf16)

__device__ __forceinline__ void gload_lds16(const void* g, void* lds) {
  __builtin_amdgcn_global_load_lds(
      (const __attribute__((address_space(1))) unsigned int*)g,
      (__attribute__((address_space(3))) unsigned int*)lds, 16, 0, 0);
}

__device__ __forceinline__ bfrag ldb(const bf16* p) {
  return *(const bfrag*)p;
}

// pack two f32 -> one dword of 2 bf16 (compiler emits v_cvt_pk_bf16_f32)
__device__ __forceinline__ unsigned pack2(float lo, float hi) {
  union { bf16x2 h; unsigned u; } c;
  c.h = bf16x2{(bf16)lo, (bf16)hi};
  return c.u;
}

// v_permlane32_swap_b32 via the documented gfx950 builtin.
// After: a[l] = l<32 ? a_old[l] : b_old[l-32];  b[l] = l<32 ? a_old[l+32] : b_old[l]
__device__ __forceinline__ void plswap(unsigned& a, unsigned& b) {
  u32x2 r = __builtin_amdgcn_permlane32_swap(a, b, false, false);
  a = r.x;
  b = r.y;
}

__device__ __forceinline__ f32x16 zero16() {
  f32x16 z;
#pragma unroll
  for (int i = 0; i < 16; ++i) z[i] = 0.f;
  return z;
}

// ---------------------------------------------------------------------------
// Fused prep: fp32->bf16 of three tensors + mask bit-pack, one launch.
// blocks [0,4096): iQ  [4096,5632): Wa  [5632,6144): Wo  [6144,8192): mask
// ---------------------------------------------------------------------------
__global__ __launch_bounds__(256) void prep(const float* __restrict__ s0,
                                            const float* __restrict__ s1,
                                            const float* __restrict__ s2,
                                            bf16* __restrict__ d0,
                                            bf16* __restrict__ d1,
                                            bf16* __restrict__ d2,
                                            const int* __restrict__ mask,
                                            unsigned* __restrict__ bits) {
  const int blk = blockIdx.x;
  if (blk < 6144) {
    const float* s;
    bf16* d;
    size_t base;
    if (blk < 4096)      { s = s0; d = d0; base = (size_t)blk * 2048; }
    else if (blk < 5632) { s = s1; d = d1; base = (size_t)(blk - 4096) * 2048; }
    else                 { s = s2; d = d2; base = (size_t)(blk - 5632) * 2048; }
    const size_t i = base + (size_t)threadIdx.x * 8;
    const float4 a = *(const float4*)(s + i);
    const float4 b = *(const float4*)(s + i + 4);
    bfrag o = {(bf16)a.x, (bf16)a.y, (bf16)a.z, (bf16)a.w,
               (bf16)b.x, (bf16)b.y, (bf16)b.z, (bf16)b.w};
    *(bfrag*)(d + i) = o;
  } else {
    const int w = (blk - 6144) * 256 + threadIdx.x;
    const int4* p = (const int4*)(mask + (size_t)w * 32);
    unsigned out = 0;
#pragma unroll
    for (int i = 0; i < 8; ++i) {
      int4 m = p[i];
      out |= (unsigned)(m.x != 0) << (i * 4);
      out |= (unsigned)(m.y != 0) << (i * 4 + 1);
      out |= (unsigned)(m.z != 0) << (i * 4 + 2);
      out |= (unsigned)(m.w != 0) << (i * 4 + 3);
    }
    bits[w] = out;
  }
}

// ---------------------------------------------------------------------------
// GEMM C = A * B^T  (A:[M][K], Bm:[N][K], bf16 in, fp32 accum)
// MODE 0: A row-major; epilogue scatters bf16 Q(x0.125*log2e)/K/Vt(transposed)
// MODE 1: A in head-split layout [b][h][s][64]; fp32 store to Cf[M][Ndim]
// Round-19: T1 bijective XCD-chunked block swizzle. Default dispatch maps
// bid==c (mod 8) to XCD c; with gridDim.x % 8 == 0 each XCD sees a FIXED n0
// set but ALL m0 A-panels -> A fetched 8x (gemm0 ~128 MB, gemm1 ~128 MB).
// Swizzle swz=(bid&7)*(nwg/8)+(bid>>3) gives each XCD 8 consecutive m-panels
// (2 MB, L2-resident, fetched once chip-wide) x all n0. nwg%8==0 for both
// grids (1536, 512) so this simple form is bijective.
// ---------------------------------------------------------------------------
template <int MODE>
__global__ __launch_bounds__(256) void gemm_bt(
    const bf16* __restrict__ A,
    const bf16* __restrict__ Bm,
    bf16* __restrict__ C0,
    bf16* __restrict__ C1,
    bf16* __restrict__ C2,
    float* __restrict__ Cf,
    int Kdim, int Ndim)
{
  __shared__ __align__(16) bf16 As[128 * 32];
  __shared__ __align__(16) bf16 Bs[128 * 32];

  const int tid  = threadIdx.x;
  const int wave = tid >> 6;
  const int lane = tid & 63;
  const int n16  = lane & 15;
  const int quad = lane >> 4;
  const int wm   = wave & 1;
  const int wn   = wave >> 1;
  // T1 XCD-chunked swizzle (bijective since nwg % 8 == 0)
  const int bid  = blockIdx.y * gridDim.x + blockIdx.x;
  const int nwg  = gridDim.x * gridDim.y;
  const int swz  = (bid & 7) * (nwg >> 3) + (bid >> 3);
  const int m0   = (swz / gridDim.x) * 128;
  const int n0   = (swz % gridDim.x) * 128;

  const f32x4 fzero = {0.f, 0.f, 0.f, 0.f};
  f32x4 acc[4][4];
#pragma unroll
  for (int i = 0; i < 4; ++i)
#pragma unroll
    for (int j = 0; j < 4; ++j) acc[i][j] = fzero;

  const int lcol = (lane & 3) * 8;  // element offset within the 32-elem LDS row

  for (int k0 = 0; k0 < Kdim; k0 += 32) {
#pragma unroll
    for (int c = 0; c < 2; ++c) {
      const int chunk = wave * 2 + c;          // 0..7, 16 rows each
      const int row   = chunk * 16 + (lane >> 2);
      const bf16* agp;
      if (MODE == 0) {
        agp = A + (size_t)(m0 + row) * Kdim + k0 + lcol;
      } else {
        // A = O in head-split layout [b][h][s][64]; head h = k0>>6.
        const int gs = m0 + row;               // global row (b*2048 + s)
        const int h  = k0 >> 6;
        agp = A + (((size_t)(gs >> 11) * Hc + h) * Sc + (gs & 2047)) * ADc
                + (k0 & 63) + lcol;
      }
      gload_lds16(agp, (char*)As + chunk * 1024);
      gload_lds16(Bm + (size_t)(n0 + row) * Kdim + k0 + lcol,
                  (char*)Bs + chunk * 1024);
    }
    __syncthreads();

    bfrag af[4], bf[4];
#pragma unroll
    for (int i = 0; i < 4; ++i)
      af[i] = ldb(As + (wm * 64 + i * 16 + n16) * 32 + quad * 8);
#pragma unroll
    for (int j = 0; j < 4; ++j)
      bf[j] = ldb(Bs + (wn * 64 + j * 16 + n16) * 32 + quad * 8);
#pragma unroll
    for (int i = 0; i < 4; ++i)
#pragma unroll
      for (int j = 0; j < 4; ++j)
        acc[i][j] = __builtin_amdgcn_mfma_f32_16x16x32_bf16(af[i], bf[j], acc[i][j], 0, 0, 0);
    __syncthreads();
  }

#pragma unroll
  for (int i = 0; i < 4; ++i) {
    const int grow = m0 + wm * 64 + i * 16 + quad * 4;
#pragma unroll
    for (int j = 0; j < 4; ++j) {
      const int col_local = wn * 64 + j * 16 + n16;
#pragma unroll
      for (int r = 0; r < 4; ++r) {
        const int row = grow + r;
        const float v = acc[i][j][r];
        if (MODE == 1) {
          Cf[(size_t)row * Ndim + n0 + col_local] = v;   // fp32 final output
        } else {
          const int seg = n0 >> 10;               // 0=Q 1=K 2=V (uniform per block)
          const int hid = (n0 & 1023) + col_local;
          const int h = hid >> 6, a = hid & 63;
          const int bi = row >> 11, s = row & 2047;
          if (seg == 0)
            // Q pre-scaled by (1/sqrt(64))*log2(e): attn computes exp2(Q.K).
            // Still ONE bf16 rounding of the f32 accumulator (same error
            // magnitude as the old 0.125 scale) -- not an extra layer.
            C0[(((size_t)bi * Hc + h) * Sc + s) * ADc + a] = (bf16)(v * 0.18033688011112042f);
          else if (seg == 1)
            C1[(((size_t)bi * Hc + h) * Sc + s) * ADc + a] = (bf16)v;
          else                // V stored transposed: Vt[bh][a][s]
            C2[(((size_t)bi * Hc + h) * ADc + a) * Sc + s] = (bf16)v;
        }
      }
    }
  }
}

// ---------------------------------------------------------------------------
// Flash attention, flat softmax (round-18 kernel, unchanged in round-19).
// 128 keys per barrier, DMA-staged double-buffered LDS (Ks/Vs[2][2], 64 KB),
// 16 barriers total. All math verified through R11 (passed, absmax 0.0024):
// swapped QK^T via 32x32x16 MFMA (P[query=lane&31][16 keys] in regs),
// raw-exp2 softmax (log2e folded into Q prescale), MFMA denominator
// dacc=mfma(P,ones) sharing of0's r<->query layout, PV A-frags in-register
// via cvt_pk+permlane32_swap (zero-LDS P), XCD-locality block decode
// (bh=blk&63, FETCH 41 MB confirmed), source-side XOR swizzle with linear
// DMA dest. R11 measured: 106.3 us, MfmaUtil 34.5, VALU 58, no spill.
// ---------------------------------------------------------------------------
__global__ __launch_bounds__(512, 4) void attn(
    const bf16* __restrict__ Qw,
    const bf16* __restrict__ Kw,
    const bf16* __restrict__ Vtw,
    const unsigned* __restrict__ mbits,
    bf16* __restrict__ Ow)   // == Qw (aliased)
{
  __shared__ __align__(16) bf16 Ks[2][2][64 * 64];  // [dbuf][keyhalf][key][dim]
  __shared__ __align__(16) bf16 Vs[2][2][64 * 64];  // [dbuf][keyhalf][dim][key]

  const int tid  = threadIdx.x;
  const int wave = tid >> 6, lane = tid & 63;
  const int l31  = lane & 31, hi = lane >> 5;
  const int sw   = lane & 7;                        // xor-swizzle key (row&7)
  // XCD-locality decode: blocks of one bh differ by 64 in blockIdx -> all
  // congruent mod 8 -> same XCD L2 serves that bh's K/V.
  const int bh   = blockIdx.x & 63, qb = blockIdx.x >> 6;
  const int b    = bh >> 4;
  const int q0w  = qb * 256 + wave * 32;

  // DMA source coords: lane l of wave w covers LDS chunk w*64+l, i.e.
  // row = w*8 + (l>>3); it must fetch global chunk (l&7) ^ (row&7) of that
  // row, and (row&7) == (l>>3). Element offset = chunk*8.
  const int drow = wave * 8 + (lane >> 3);
  const int dchk = ((lane & 7) ^ (lane >> 3)) * 8;
  const bf16* gK = Kw  + ((size_t)bh * Sc + drow) * ADc + dchk;  // +kt*128*ADc
  const bf16* gV = Vtw + ((size_t)bh * ADc + drow) * Sc + dchk;  // +kt*128
  const int ldsb = wave * 1024;                     // wave-uniform byte base

  // Q B-frags, resident (pre-scaled by 0.125*log2e): row = query q0w+l31,
  // MFMA k = 8*hi + j  ->  element 16*ks + 8*hi + j
  const bf16* qrow = Qw + ((size_t)bh * Sc + q0w + l31) * ADc + hi * 8;
  bfrag qf[4];
#pragma unroll
  for (int ks = 0; ks < 4; ++ks) qf[ks] = ldb(qrow + ks * 16);

  // all-ones B-frag for the denominator MFMA
  bfrag onef;
#pragma unroll
  for (int i = 0; i < 8; ++i) onef[i] = (bf16)1.0f;

  f32x16 of0  = zero16();   // O[query][dim 0..31]
  f32x16 of1  = zero16();   // O[query][dim 32..63]
  f32x16 dacc = zero16();   // denominator, same r<->query layout as of0/of1

  // one mask row per lane: its query q0w+l31; 128 key-bits per iter = uint4
  const unsigned* mq = mbits + ((size_t)b * Sc + q0w + l31) * (Sc / 32);

  // one 64-key half: QK^T (swapped) -> exp2/mask/pack -> PV + denom MFMA
  auto tile_compute = [&](const bf16* Kbuf, const bf16* Vbuf, unsigned mx,
                          unsigned my) {
#pragma unroll
    for (int nt = 0; nt < 2; ++nt) {
      // S^T subtile: D[key 32nt+..][query], key = (r&3)+8*(r>>2)+4*hi
      f32x16 sf = zero16();
#pragma unroll
      for (int ks = 0; ks < 4; ++ks) {
        const bfrag kf = ldb(Kbuf + (nt * 32 + l31) * 64 + (((2 * ks + hi) ^ sw) * 8));
        sf = __builtin_amdgcn_mfma_f32_32x32x16_bf16(kf, qf[ks], sf, 0, 0, 0);
      }

      // softmax: exp2 via raw v_exp_f32 intrinsic (log2e pre-folded into Q),
      // mask bit (r&3)+8*(r>>2) after pre-shift by 4*hi, pack to bf16 dwords
      const unsigned w = (nt ? my : mx) >> (hi * 4);
      unsigned D[8];
#pragma unroll
      for (int m = 0; m < 8; ++m) {
        const int r0 = 2 * m, r1 = r0 + 1;
        float p0 = __builtin_amdgcn_exp2f(sf[r0]);
        float p1 = __builtin_amdgcn_exp2f(sf[r1]);
        if ((w >> ((r0 & 3) + 8 * (r0 >> 2))) & 1u) p0 = 0.f;
        if ((w >> ((r1 & 3) + 8 * (r1 >> 2))) & 1u) p1 = 0.f;
        D[m] = pack2(p0, p1);
      }

      // P A-frags via permlane32_swap (keys 32nt+16a+8hi+j at elem j),
      // then PV + denominator MFMA (B = ones: D[q][*] = sum_k P[q][k])
#pragma unroll
      for (int a = 0; a < 2; ++a) {
        unsigned w0 = D[4 * a + 0], w2 = D[4 * a + 2];
        plswap(w0, w2);
        unsigned w1 = D[4 * a + 1], w3 = D[4 * a + 3];
        plswap(w1, w3);
        union { unsigned u[4]; bfrag f; } pu;
        pu.u[0] = w0; pu.u[1] = w1; pu.u[2] = w2; pu.u[3] = w3;
        const int vg = ((4 * nt + 2 * a + hi) ^ sw) * 8;
        const bfrag vf0 = ldb(Vbuf + l31 * 64 + vg);
        of0 = __builtin_amdgcn_mfma_f32_32x32x16_bf16(pu.f, vf0, of0, 0, 0, 0);
        const bfrag vf1 = ldb(Vbuf + (32 + l31) * 64 + vg);
        of1 = __builtin_amdgcn_mfma_f32_32x32x16_bf16(pu.f, vf1, of1, 0, 0, 0);
        dacc = __builtin_amdgcn_mfma_f32_32x32x16_bf16(pu.f, onef, dacc, 0, 0, 0);
      }
    }
  };

  // async-DMA stage of 128-key tile kt into dbuf buf (4 x 16B per thread)
  auto stage = [&](int buf, int kt) {
    const bf16* k0 = gK + (size_t)kt * 128 * ADc;
    const bf16* v0 = gV + (size_t)kt * 128;
    gload_lds16(k0,            (char*)Ks[buf][0] + ldsb);
    gload_lds16(k0 + 64 * ADc, (char*)Ks[buf][1] + ldsb);
    gload_lds16(v0,            (char*)Vs[buf][0] + ldsb);
    gload_lds16(v0 + 64,       (char*)Vs[buf][1] + ldsb);
  };

  // prologue: stage tile 0; __syncthreads' implicit vmcnt(0) covers the DMA
  stage(0, 0);
  __syncthreads();

  for (int kt = 0; kt < Sc / 128; ++kt) {
    const int cur = kt & 1;
    if (kt + 1 < Sc / 128) stage(cur ^ 1, kt + 1);  // async; hidden by compute

    const uint4 mwv = *(const uint4*)(mq + kt * 4);
    tile_compute(Ks[cur][0], Vs[cur][0], mwv.x, mwv.y);
    tile_compute(Ks[cur][1], Vs[cur][1], mwv.z, mwv.w);

    __syncthreads();   // drains this wave's DMA (vmcnt 0) + all waves synced
  }

  // epilogue: normalize directly -- of0[r] and dacc[r] share the same query
#pragma unroll
  for (int r = 0; r < 16; ++r) {
    const int query = (r & 3) + 8 * (r >> 2) + 4 * hi;
    const float invr = 1.f / dacc[r];
    bf16* orow = Ow + ((size_t)bh * Sc + q0w + query) * ADc + l31;
    orow[0]  = (bf16)(of0[r] * invr);
    orow[32] = (bf16)(of1[r] * invr);
  }
}

extern "C" void kernel_launch(void* const* d_in, const int* in_sizes, int n_in,
                              void* d_out, int out_size, void* d_ws, size_t ws_size,
                              hipStream_t stream) {
  const float* iQ = (const float*)d_in[0];
  const int* mask = (const int*)d_in[1];
  const float* Wa = (const float*)d_in[2];
  const float* Wo = (const float*)d_in[3];
  float* out      = (float*)d_out;   // 8.4M fp32 = 32 MB

  // d_out doubles as scratch until the final GEMM overwrites all of it:
  bf16* iQb       = (bf16*)d_out;                     // 16 MB
  bf16* Wab       = iQb + QKV_ELEMS;                  // 6 MB
  unsigned* mbits = (unsigned*)(Wab + 3145728);       // 2 MB
  // Workspace (50 MB): Q/O share a buffer; Wob read by the final GEMM.
  bf16* Qw  = (bf16*)d_ws;        // 16 MB (Q, then O)
  bf16* Kw  = Qw + QKV_ELEMS;     // 16 MB
  bf16* Vtw = Kw + QKV_ELEMS;     // 16 MB
  bf16* Wob = Vtw + QKV_ELEMS;    // 2 MB

  prep<<<dim3(8192), 256, 0, stream>>>(iQ, Wa, Wo, iQb, Wab, Wob, mask, mbits);
  gemm_bt<0><<<dim3(24, 64), 256, 0, stream>>>(iQb, Wab, Qw, Kw, Vtw, nullptr, 1024, 3072);
  attn<<<dim3(Bc * Hc * 8), 512, 0, stream>>>(Qw, Kw, Vtw, mbits, Qw);
  gemm_bt<1><<<dim3(8, 64), 256, 0, stream>>>(Qw, Wob, nullptr, nullptr, nullptr, out, 1024, 1024);
}

// Round 14
// 337.592 us; speedup vs baseline: 1.0848x; 1.0848x over previous
//
#include <hip/hip_runtime.h>
#include <hip/hip_bf16.h>

// All external tensors are FLOAT32; bf16 is used only internally for MFMA.
typedef __bf16 bf16;
typedef __bf16 bfrag __attribute__((ext_vector_type(8)));   // 8 bf16 = 4 VGPRs (MFMA A/B)
typedef __bf16 bf16x2 __attribute__((ext_vector_type(2)));  // cvt_pk pair
typedef __bf16 bf16x4 __attribute__((ext_vector_type(4)));  // packed 8B store
typedef float f32x4 __attribute__((ext_vector_type(4)));    // 16x16 MFMA C/D
typedef float f32x16 __attribute__((ext_vector_type(16)));  // 32x32 MFMA C/D
typedef unsigned u32x2 __attribute__((ext_vector_type(2))); // permlane32_swap result

constexpr int Bc = 4, Sc = 2048, Hc = 16, ADc = 64, HIDc = 1024;
constexpr size_t QKV_ELEMS = (size_t)Bc * Hc * Sc * ADc;    // 8388608 (16 MB bf16)

__device__ __forceinline__ void gload_lds16(const void* g, void* lds) {
  __builtin_amdgcn_global_load_lds(
      (const __attribute__((address_space(1))) unsigned int*)g,
      (__attribute__((address_space(3))) unsigned int*)lds, 16, 0, 0);
}

__device__ __forceinline__ bfrag ldb(const bf16* p) {
  return *(const bfrag*)p;
}

// pack two f32 -> one dword of 2 bf16 (compiler emits v_cvt_pk_bf16_f32)
__device__ __forceinline__ unsigned pack2(float lo, float hi) {
  union { bf16x2 h; unsigned u; } c;
  c.h = bf16x2{(bf16)lo, (bf16)hi};
  return c.u;
}

// v_permlane32_swap_b32 via the documented gfx950 builtin.
// After: a[l] = l<32 ? a_old[l] : b_old[l-32];  b[l] = l<32 ? a_old[l+32] : b_old[l]
__device__ __forceinline__ void plswap(unsigned& a, unsigned& b) {
  u32x2 r = __builtin_amdgcn_permlane32_swap(a, b, false, false);
  a = r.x;
  b = r.y;
}

__device__ __forceinline__ f32x16 zero16() {
  f32x16 z;
#pragma unroll
  for (int i = 0; i < 16; ++i) z[i] = 0.f;
  return z;
}

// ---------------------------------------------------------------------------
// Fused prep: fp32->bf16 of three tensors + mask bit-pack, one launch.
// blocks [0,4096): iQ  [4096,5632): Wa  [5632,6144): Wo  [6144,8192): mask
// ---------------------------------------------------------------------------
__global__ __launch_bounds__(256) void prep(const float* __restrict__ s0,
                                            const float* __restrict__ s1,
                                            const float* __restrict__ s2,
                                            bf16* __restrict__ d0,
                                            bf16* __restrict__ d1,
                                            bf16* __restrict__ d2,
                                            const int* __restrict__ mask,
                                            unsigned* __restrict__ bits) {
  const int blk = blockIdx.x;
  if (blk < 6144) {
    const float* s;
    bf16* d;
    size_t base;
    if (blk < 4096)      { s = s0; d = d0; base = (size_t)blk * 2048; }
    else if (blk < 5632) { s = s1; d = d1; base = (size_t)(blk - 4096) * 2048; }
    else                 { s = s2; d = d2; base = (size_t)(blk - 5632) * 2048; }
    const size_t i = base + (size_t)threadIdx.x * 8;
    const float4 a = *(const float4*)(s + i);
    const float4 b = *(const float4*)(s + i + 4);
    bfrag o = {(bf16)a.x, (bf16)a.y, (bf16)a.z, (bf16)a.w,
               (bf16)b.x, (bf16)b.y, (bf16)b.z, (bf16)b.w};
    *(bfrag*)(d + i) = o;
  } else {
    const int w = (blk - 6144) * 256 + threadIdx.x;
    const int4* p = (const int4*)(mask + (size_t)w * 32);
    unsigned out = 0;
#pragma unroll
    for (int i = 0; i < 8; ++i) {
      int4 m = p[i];
      out |= (unsigned)(m.x != 0) << (i * 4);
      out |= (unsigned)(m.y != 0) << (i * 4 + 1);
      out |= (unsigned)(m.z != 0) << (i * 4 + 2);
      out |= (unsigned)(m.w != 0) << (i * 4 + 3);
    }
    bits[w] = out;
  }
}

// ---------------------------------------------------------------------------
// GEMM C = A * B^T  (A:[M][K], Bm:[N][K], bf16 in, fp32 accum)
// MODE 0: A row-major; epilogue scatters bf16 Q(x0.125*log2e)/K/Vt(transposed)
// MODE 1: A in head-split layout [b][h][s][64]; fp32 store to Cf[M][Ndim]
// Round-21 == round-20 resubmit (R13's bench died to container infra, no
// kernel verdict; source re-audited -- staging XOR involution, MODE-1 k0&63=0,
// aligned bf16x4 Vt store all check out).
// BK 32->64 (halves the per-K-step vmcnt(0)+barrier drains: the K=1024 loop
// runs 16 iterations instead of 32). 64-col rows (128B) would be a 16-way
// LDS read conflict, so the tile is XOR-swizzled: linear gload_lds dest +
// source-side granule swizzle g^=(row&7) (rule 21; same proven pattern as
// the attn kernel), frag reads at granule (ks*4+quad)^(n16&7).
// Also: Vt epilogue store vectorized -- the 4 r-consecutive acc values are
// s-consecutive in Vt, one 8B bf16x4 store replaces 4 scattered 2B stores.
// T1 XCD-chunked block swizzle kept from R19 (null but harmless).
// ---------------------------------------------------------------------------
template <int MODE>
__global__ __launch_bounds__(256) void gemm_bt(
    const bf16* __restrict__ A,
    const bf16* __restrict__ Bm,
    bf16* __restrict__ C0,
    bf16* __restrict__ C1,
    bf16* __restrict__ C2,
    float* __restrict__ Cf,
    int Kdim, int Ndim)
{
  __shared__ __align__(16) bf16 As[128 * 64];   // [row][64], XOR-swizzled
  __shared__ __align__(16) bf16 Bs[128 * 64];

  const int tid  = threadIdx.x;
  const int wave = tid >> 6;
  const int lane = tid & 63;
  const int n16  = lane & 15;
  const int quad = lane >> 4;
  const int wm   = wave & 1;
  const int wn   = wave >> 1;
  // T1 XCD-chunked swizzle (bijective since nwg % 8 == 0)
  const int bid  = blockIdx.y * gridDim.x + blockIdx.x;
  const int nwg  = gridDim.x * gridDim.y;
  const int swz  = (bid & 7) * (nwg >> 3) + (bid >> 3);
  const int m0   = (swz / gridDim.x) * 128;
  const int n0   = (swz % gridDim.x) * 128;

  const f32x4 fzero = {0.f, 0.f, 0.f, 0.f};
  f32x4 acc[4][4];
#pragma unroll
  for (int i = 0; i < 4; ++i)
#pragma unroll
    for (int j = 0; j < 4; ++j) acc[i][j] = fzero;

  // staging: issue c covers LDS rows [c*32, c*32+32); thread t -> row
  // c*32 + (t>>3), src granule (t&7)^((t>>3)&7) (XOR swizzle, source side).
  const int srow8 = tid >> 3;                       // row within 32-row group
  const int dg    = (((tid & 7) ^ ((tid >> 3) & 7))) * 8;  // src elem offset
  const int fsw   = n16 & 7;                        // frag-read swizzle key

  for (int k0 = 0; k0 < Kdim; k0 += 64) {
#pragma unroll
    for (int c = 0; c < 4; ++c) {
      const int arow = c * 32 + srow8;
      const bf16* agp;
      if (MODE == 0) {
        agp = A + (size_t)(m0 + arow) * Kdim + k0 + dg;
      } else {
        // A = O in head-split layout [b][h][s][64]; head h = k0>>6.
        const int gs = m0 + arow;              // global row (b*2048 + s)
        const int h  = k0 >> 6;
        agp = A + (((size_t)(gs >> 11) * Hc + h) * Sc + (gs & 2047)) * ADc + dg;
      }
      gload_lds16(agp, (char*)As + wave * 1024 + c * 4096);
      gload_lds16(Bm + (size_t)(n0 + arow) * Kdim + k0 + dg,
                  (char*)Bs + wave * 1024 + c * 4096);
    }
    __syncthreads();

#pragma unroll
    for (int ks = 0; ks < 2; ++ks) {
      const int go = ((ks * 4 + quad) ^ fsw) * 8;   // swizzled elem offset
      bfrag af[4], bf[4];
#pragma unroll
      for (int i = 0; i < 4; ++i)
        af[i] = ldb(As + (wm * 64 + i * 16 + n16) * 64 + go);
#pragma unroll
      for (int j = 0; j < 4; ++j)
        bf[j] = ldb(Bs + (wn * 64 + j * 16 + n16) * 64 + go);
#pragma unroll
      for (int i = 0; i < 4; ++i)
#pragma unroll
        for (int j = 0; j < 4; ++j)
          acc[i][j] = __builtin_amdgcn_mfma_f32_16x16x32_bf16(af[i], bf[j], acc[i][j], 0, 0, 0);
    }
    __syncthreads();
  }

#pragma unroll
  for (int i = 0; i < 4; ++i) {
    const int grow = m0 + wm * 64 + i * 16 + quad * 4;
#pragma unroll
    for (int j = 0; j < 4; ++j) {
      const int col_local = wn * 64 + j * 16 + n16;
      const int seg = n0 >> 10;                 // 0=Q 1=K 2=V (uniform, MODE 0)
      if (MODE == 0 && seg == 2) {
        // V stored transposed Vt[bh][a][s]: r=0..3 are s-consecutive -> one
        // 8B packed store (same addresses/values as 4 scalar stores).
        const int hid = (n0 & 1023) + col_local;
        const int h = hid >> 6, a = hid & 63;
        const int bi = grow >> 11, s0 = grow & 2047;
        bf16x4 v4;
#pragma unroll
        for (int r = 0; r < 4; ++r) v4[r] = (bf16)acc[i][j][r];
        *(bf16x4*)(C2 + (((size_t)bi * Hc + h) * ADc + a) * Sc + s0) = v4;
      } else {
#pragma unroll
        for (int r = 0; r < 4; ++r) {
          const int row = grow + r;
          const float v = acc[i][j][r];
          if (MODE == 1) {
            Cf[(size_t)row * Ndim + n0 + col_local] = v;   // fp32 final output
          } else {
            const int hid = (n0 & 1023) + col_local;
            const int h = hid >> 6, a = hid & 63;
            const int bi = row >> 11, s = row & 2047;
            if (seg == 0)
              // Q pre-scaled by (1/sqrt(64))*log2(e): attn computes exp2(Q.K).
              C0[(((size_t)bi * Hc + h) * Sc + s) * ADc + a] = (bf16)(v * 0.18033688011112042f);
            else
              C1[(((size_t)bi * Hc + h) * Sc + s) * ADc + a] = (bf16)v;
          }
        }
      }
    }
  }
}

// ---------------------------------------------------------------------------
// Flash attention, flat softmax (round-18 kernel, unchanged; control).
// 128 keys per barrier, DMA-staged double-buffered LDS (Ks/Vs[2][2], 64 KB),
// 16 barriers total. All math verified through R12 (passed, absmax 0.0024):
// swapped QK^T via 32x32x16 MFMA (P[query=lane&31][16 keys] in regs),
// raw-exp2 softmax (log2e folded into Q prescale), MFMA denominator
// dacc=mfma(P,ones) sharing of0's r<->query layout, PV A-frags in-register
// via cvt_pk+permlane32_swap (zero-LDS P), XCD-locality block decode
// (bh=blk&63, FETCH 41 MB confirmed), source-side XOR swizzle with linear
// DMA dest. R12 measured: 106.5 us, MfmaUtil 34.7, VALU 59, no spill.
// ---------------------------------------------------------------------------
__global__ __launch_bounds__(512, 4) void attn(
    const bf16* __restrict__ Qw,
    const bf16* __restrict__ Kw,
    const bf16* __restrict__ Vtw,
    const unsigned* __restrict__ mbits,
    bf16* __restrict__ Ow)   // == Qw (aliased)
{
  __shared__ __align__(16) bf16 Ks[2][2][64 * 64];  // [dbuf][keyhalf][key][dim]
  __shared__ __align__(16) bf16 Vs[2][2][64 * 64];  // [dbuf][keyhalf][dim][key]

  const int tid  = threadIdx.x;
  const int wave = tid >> 6, lane = tid & 63;
  const int l31  = lane & 31, hi = lane >> 5;
  const int sw   = lane & 7;                        // xor-swizzle key (row&7)
  // XCD-locality decode: blocks of one bh differ by 64 in blockIdx -> all
  // congruent mod 8 -> same XCD L2 serves that bh's K/V.
  const int bh   = blockIdx.x & 63, qb = blockIdx.x >> 6;
  const int b    = bh >> 4;
  const int q0w  = qb * 256 + wave * 32;

  // DMA source coords: lane l of wave w covers LDS chunk w*64+l, i.e.
  // row = w*8 + (l>>3); it must fetch global chunk (l&7) ^ (row&7) of that
  // row, and (row&7) == (l>>3). Element offset = chunk*8.
  const int drow = wave * 8 + (lane >> 3);
  const int dchk = ((lane & 7) ^ (lane >> 3)) * 8;
  const bf16* gK = Kw  + ((size_t)bh * Sc + drow) * ADc + dchk;  // +kt*128*ADc
  const bf16* gV = Vtw + ((size_t)bh * ADc + drow) * Sc + dchk;  // +kt*128
  const int ldsb = wave * 1024;                     // wave-uniform byte base

  // Q B-frags, resident (pre-scaled by 0.125*log2e): row = query q0w+l31,
  // MFMA k = 8*hi + j  ->  element 16*ks + 8*hi + j
  const bf16* qrow = Qw + ((size_t)bh * Sc + q0w + l31) * ADc + hi * 8;
  bfrag qf[4];
#pragma unroll
  for (int ks = 0; ks < 4; ++ks) qf[ks] = ldb(qrow + ks * 16);

  // all-ones B-frag for the denominator MFMA
  bfrag onef;
#pragma unroll
  for (int i = 0; i < 8; ++i) onef[i] = (bf16)1.0f;

  f32x16 of0  = zero16();   // O[query][dim 0..31]
  f32x16 of1  = zero16();   // O[query][dim 32..63]
  f32x16 dacc = zero16();   // denominator, same r<->query layout as of0/of1

  // one mask row per lane: its query q0w+l31; 128 key-bits per iter = uint4
  const unsigned* mq = mbits + ((size_t)b * Sc + q0w + l31) * (Sc / 32);

  // one 64-key half: QK^T (swapped) -> exp2/mask/pack -> PV + denom MFMA
  auto tile_compute = [&](const bf16* Kbuf, const bf16* Vbuf, unsigned mx,
                          unsigned my) {
#pragma unroll
    for (int nt = 0; nt < 2; ++nt) {
      // S^T subtile: D[key 32nt+..][query], key = (r&3)+8*(r>>2)+4*hi
      f32x16 sf = zero16();
#pragma unroll
      for (int ks = 0; ks < 4; ++ks) {
        const bfrag kf = ldb(Kbuf + (nt * 32 + l31) * 64 + (((2 * ks + hi) ^ sw) * 8));
        sf = __builtin_amdgcn_mfma_f32_32x32x16_bf16(kf, qf[ks], sf, 0, 0, 0);
      }

      // softmax: exp2 via raw v_exp_f32 intrinsic (log2e pre-folded into Q),
      // mask bit (r&3)+8*(r>>2) after pre-shift by 4*hi, pack to bf16 dwords
      const unsigned w = (nt ? my : mx) >> (hi * 4);
      unsigned D[8];
#pragma unroll
      for (int m = 0; m < 8; ++m) {
        const int r0 = 2 * m, r1 = r0 + 1;
        float p0 = __builtin_amdgcn_exp2f(sf[r0]);
        float p1 = __builtin_amdgcn_exp2f(sf[r1]);
        if ((w >> ((r0 & 3) + 8 * (r0 >> 2))) & 1u) p0 = 0.f;
        if ((w >> ((r1 & 3) + 8 * (r1 >> 2))) & 1u) p1 = 0.f;
        D[m] = pack2(p0, p1);
      }

      // P A-frags via permlane32_swap (keys 32nt+16a+8hi+j at elem j),
      // then PV + denominator MFMA (B = ones: D[q][*] = sum_k P[q][k])
#pragma unroll
      for (int a = 0; a < 2; ++a) {
        unsigned w0 = D[4 * a + 0], w2 = D[4 * a + 2];
        plswap(w0, w2);
        unsigned w1 = D[4 * a + 1], w3 = D[4 * a + 3];
        plswap(w1, w3);
        union { unsigned u[4]; bfrag f; } pu;
        pu.u[0] = w0; pu.u[1] = w1; pu.u[2] = w2; pu.u[3] = w3;
        const int vg = ((4 * nt + 2 * a + hi) ^ sw) * 8;
        const bfrag vf0 = ldb(Vbuf + l31 * 64 + vg);
        of0 = __builtin_amdgcn_mfma_f32_32x32x16_bf16(pu.f, vf0, of0, 0, 0, 0);
        const bfrag vf1 = ldb(Vbuf + (32 + l31) * 64 + vg);
        of1 = __builtin_amdgcn_mfma_f32_32x32x16_bf16(pu.f, vf1, of1, 0, 0, 0);
        dacc = __builtin_amdgcn_mfma_f32_32x32x16_bf16(pu.f, onef, dacc, 0, 0, 0);
      }
    }
  };

  // async-DMA stage of 128-key tile kt into dbuf buf (4 x 16B per thread)
  auto stage = [&](int buf, int kt) {
    const bf16* k0 = gK + (size_t)kt * 128 * ADc;
    const bf16* v0 = gV + (size_t)kt * 128;
    gload_lds16(k0,            (char*)Ks[buf][0] + ldsb);
    gload_lds16(k0 + 64 * ADc, (char*)Ks[buf][1] + ldsb);
    gload_lds16(v0,            (char*)Vs[buf][0] + ldsb);
    gload_lds16(v0 + 64,       (char*)Vs[buf][1] + ldsb);
  };

  // prologue: stage tile 0; __syncthreads' implicit vmcnt(0) covers the DMA
  stage(0, 0);
  __syncthreads();

  for (int kt = 0; kt < Sc / 128; ++kt) {
    const int cur = kt & 1;
    if (kt + 1 < Sc / 128) stage(cur ^ 1, kt + 1);  // async; hidden by compute

    const uint4 mwv = *(const uint4*)(mq + kt * 4);
    tile_compute(Ks[cur][0], Vs[cur][0], mwv.x, mwv.y);
    tile_compute(Ks[cur][1], Vs[cur][1], mwv.z, mwv.w);

    __syncthreads();   // drains this wave's DMA (vmcnt 0) + all waves synced
  }

  // epilogue: normalize directly -- of0[r] and dacc[r] share the same query
#pragma unroll
  for (int r = 0; r < 16; ++r) {
    const int query = (r & 3) + 8 * (r >> 2) + 4 * hi;
    const float invr = 1.f / dacc[r];
    bf16* orow = Ow + ((size_t)bh * Sc + q0w + query) * ADc + l31;
    orow[0]  = (bf16)(of0[r] * invr);
    orow[32] = (bf16)(of1[r] * invr);
  }
}

extern "C" void kernel_launch(void* const* d_in, const int* in_sizes, int n_in,
                              void* d_out, int out_size, void* d_ws, size_t ws_size,
                              hipStream_t stream) {
  const float* iQ = (const float*)d_in[0];
  const int* mask = (const int*)d_in[1];
  const float* Wa = (const float*)d_in[2];
  const float* Wo = (const float*)d_in[3];
  float* out      = (float*)d_out;   // 8.4M fp32 = 32 MB

  // d_out doubles as scratch until the final GEMM overwrites all of it:
  bf16* iQb       = (bf16*)d_out;                     // 16 MB
  bf16* Wab       = iQb + QKV_ELEMS;                  // 6 MB
  unsigned* mbits = (unsigned*)(Wab + 3145728);       // 2 MB
  // Workspace (50 MB): Q/O share a buffer; Wob read by the final GEMM.
  bf16* Qw  = (bf16*)d_ws;        // 16 MB (Q, then O)
  bf16* Kw  = Qw + QKV_ELEMS;     // 16 MB
  bf16* Vtw = Kw + QKV_ELEMS;     // 16 MB
  bf16* Wob = Vtw + QKV_ELEMS;    // 2 MB

  prep<<<dim3(8192), 256, 0, stream>>>(iQ, Wa, Wo, iQb, Wab, Wob, mask, mbits);
  gemm_bt<0><<<dim3(24, 64), 256, 0, stream>>>(iQb, Wab, Qw, Kw, Vtw, nullptr, 1024, 3072);
  attn<<<dim3(Bc * Hc * 8), 512, 0, stream>>>(Qw, Kw, Vtw, mbits, Qw);
  gemm_bt<1><<<dim3(8, 64), 256, 0, stream>>>(Qw, Wob, nullptr, nullptr, nullptr, out, 1024, 1024);
}

// Round 15
// 327.650 us; speedup vs baseline: 1.1177x; 1.0303x over previous
//
#include <hip/hip_runtime.h>
#include <hip/hip_bf16.h>

// All external tensors are FLOAT32; bf16 is used only internally for MFMA.
typedef __bf16 bf16;
typedef __bf16 bfrag __attribute__((ext_vector_type(8)));   // 8 bf16 = 4 VGPRs (MFMA A/B)
typedef __bf16 bf16x2 __attribute__((ext_vector_type(2)));  // cvt_pk pair
typedef __bf16 bf16x4 __attribute__((ext_vector_type(4)));  // packed 8B store
typedef float f32x4 __attribute__((ext_vector_type(4)));    // 16x16 MFMA C/D
typedef float f32x16 __attribute__((ext_vector_type(16)));  // 32x32 MFMA C/D
typedef unsigned u32x2 __attribute__((ext_vector_type(2))); // permlane32_swap result

constexpr int Bc = 4, Sc = 2048, Hc = 16, ADc = 64, HIDc = 1024;
constexpr size_t QKV_ELEMS = (size_t)Bc * Hc * Sc * ADc;    // 8388608 (16 MB bf16)

__device__ __forceinline__ void gload_lds16(const void* g, void* lds) {
  __builtin_amdgcn_global_load_lds(
      (const __attribute__((address_space(1))) unsigned int*)g,
      (__attribute__((address_space(3))) unsigned int*)lds, 16, 0, 0);
}

__device__ __forceinline__ bfrag ldb(const bf16* p) {
  return *(const bfrag*)p;
}

// pack two f32 -> one dword of 2 bf16 (compiler emits v_cvt_pk_bf16_f32)
__device__ __forceinline__ unsigned pack2(float lo, float hi) {
  union { bf16x2 h; unsigned u; } c;
  c.h = bf16x2{(bf16)lo, (bf16)hi};
  return c.u;
}

// v_permlane32_swap_b32 via the documented gfx950 builtin.
// After: a[l] = l<32 ? a_old[l] : b_old[l-32];  b[l] = l<32 ? a_old[l+32] : b_old[l]
__device__ __forceinline__ void plswap(unsigned& a, unsigned& b) {
  u32x2 r = __builtin_amdgcn_permlane32_swap(a, b, false, false);
  a = r.x;
  b = r.y;
}

__device__ __forceinline__ f32x16 zero16() {
  f32x16 z;
#pragma unroll
  for (int i = 0; i < 16; ++i) z[i] = 0.f;
  return z;
}

// ---------------------------------------------------------------------------
// Fused prep: fp32->bf16 of three tensors + mask bit-pack, one launch.
// blocks [0,4096): iQ  [4096,5632): Wa  [5632,6144): Wo  [6144,8192): mask
// ---------------------------------------------------------------------------
__global__ __launch_bounds__(256) void prep(const float* __restrict__ s0,
                                            const float* __restrict__ s1,
                                            const float* __restrict__ s2,
                                            bf16* __restrict__ d0,
                                            bf16* __restrict__ d1,
                                            bf16* __restrict__ d2,
                                            const int* __restrict__ mask,
                                            unsigned* __restrict__ bits) {
  const int blk = blockIdx.x;
  if (blk < 6144) {
    const float* s;
    bf16* d;
    size_t base;
    if (blk < 4096)      { s = s0; d = d0; base = (size_t)blk * 2048; }
    else if (blk < 5632) { s = s1; d = d1; base = (size_t)(blk - 4096) * 2048; }
    else                 { s = s2; d = d2; base = (size_t)(blk - 5632) * 2048; }
    const size_t i = base + (size_t)threadIdx.x * 8;
    const float4 a = *(const float4*)(s + i);
    const float4 b = *(const float4*)(s + i + 4);
    bfrag o = {(bf16)a.x, (bf16)a.y, (bf16)a.z, (bf16)a.w,
               (bf16)b.x, (bf16)b.y, (bf16)b.z, (bf16)b.w};
    *(bfrag*)(d + i) = o;
  } else {
    const int w = (blk - 6144) * 256 + threadIdx.x;
    const int4* p = (const int4*)(mask + (size_t)w * 32);
    unsigned out = 0;
#pragma unroll
    for (int i = 0; i < 8; ++i) {
      int4 m = p[i];
      out |= (unsigned)(m.x != 0) << (i * 4);
      out |= (unsigned)(m.y != 0) << (i * 4 + 1);
      out |= (unsigned)(m.z != 0) << (i * 4 + 2);
      out |= (unsigned)(m.w != 0) << (i * 4 + 3);
    }
    bits[w] = out;
  }
}

// ---------------------------------------------------------------------------
// GEMM C = A * B^T  (A:[M][K], Bm:[N][K], bf16 in, fp32 accum)
// MODE 0: A row-major; epilogue scatters bf16 Q(x0.125*log2e)/K/Vt(transposed)
// MODE 1: A in head-split layout [b][h][s][64]; fp32 store to Cf[M][Ndim]
// Round-22: 2-phase double-buffered staging (the attn kernel's proven loop
// shape). The old loop staged the CURRENT tile then immediately barriered --
// the global->LDS DMA latency (200-900 cy) sat serially on EVERY K-step with
// no compute under it ("0-phase"). Now As/Bs[2] (BK=32, 32 KB LDS, keeps
// 5 blocks/CU): stage tile k+1 into buf^1 BEFORE computing buf; ONE barrier
// per iter (orders "done reading buf" for the next overwrite AND drains the
// prefetch DMA that had the whole compute phase to fly). BK=32 rows = 64 B
// -> 2-way LDS aliasing = free, no swizzle needed. Vt bf16x4 epilogue store
// (R14, proven) and T1 XCD block swizzle (null, harmless) kept.
// ---------------------------------------------------------------------------
template <int MODE>
__global__ __launch_bounds__(256) void gemm_bt(
    const bf16* __restrict__ A,
    const bf16* __restrict__ Bm,
    bf16* __restrict__ C0,
    bf16* __restrict__ C1,
    bf16* __restrict__ C2,
    float* __restrict__ Cf,
    int Kdim, int Ndim)
{
  __shared__ __align__(16) bf16 As[2][128 * 32];
  __shared__ __align__(16) bf16 Bs[2][128 * 32];

  const int tid  = threadIdx.x;
  const int wave = tid >> 6;
  const int lane = tid & 63;
  const int n16  = lane & 15;
  const int quad = lane >> 4;
  const int wm   = wave & 1;
  const int wn   = wave >> 1;
  // T1 XCD-chunked swizzle (bijective since nwg % 8 == 0)
  const int bid  = blockIdx.y * gridDim.x + blockIdx.x;
  const int nwg  = gridDim.x * gridDim.y;
  const int swz  = (bid & 7) * (nwg >> 3) + (bid >> 3);
  const int m0   = (swz / gridDim.x) * 128;
  const int n0   = (swz % gridDim.x) * 128;

  const f32x4 fzero = {0.f, 0.f, 0.f, 0.f};
  f32x4 acc[4][4];
#pragma unroll
  for (int i = 0; i < 4; ++i)
#pragma unroll
    for (int j = 0; j < 4; ++j) acc[i][j] = fzero;

  const int lcol = (lane & 3) * 8;  // element offset within the 32-elem LDS row
  const int srow = lane >> 2;       // row within a 16-row chunk

  // async-DMA stage of K-step k0 into dbuf buf (4 x 16B per thread)
  auto stage = [&](int buf, int k0) {
#pragma unroll
    for (int c = 0; c < 2; ++c) {
      const int chunk = wave * 2 + c;          // 0..7, 16 rows each
      const int row   = chunk * 16 + srow;
      const bf16* agp;
      if (MODE == 0) {
        agp = A + (size_t)(m0 + row) * Kdim + k0 + lcol;
      } else {
        // A = O in head-split layout [b][h][s][64]; head h = k0>>6.
        const int gs = m0 + row;               // global row (b*2048 + s)
        const int h  = k0 >> 6;
        agp = A + (((size_t)(gs >> 11) * Hc + h) * Sc + (gs & 2047)) * ADc
                + (k0 & 63) + lcol;
      }
      gload_lds16(agp, (char*)As[buf] + chunk * 1024);
      gload_lds16(Bm + (size_t)(n0 + row) * Kdim + k0 + lcol,
                  (char*)Bs[buf] + chunk * 1024);
    }
  };

  // prologue: stage K-step 0; barrier drains the DMA
  stage(0, 0);
  __syncthreads();

  for (int k0 = 0; k0 < Kdim; k0 += 32) {
    const int cur = (k0 >> 5) & 1;
    if (k0 + 32 < Kdim) stage(cur ^ 1, k0 + 32);   // async; flies under compute

    bfrag af[4], bf[4];
#pragma unroll
    for (int i = 0; i < 4; ++i)
      af[i] = ldb(As[cur] + (wm * 64 + i * 16 + n16) * 32 + quad * 8);
#pragma unroll
    for (int j = 0; j < 4; ++j)
      bf[j] = ldb(Bs[cur] + (wn * 64 + j * 16 + n16) * 32 + quad * 8);
#pragma unroll
    for (int i = 0; i < 4; ++i)
#pragma unroll
      for (int j = 0; j < 4; ++j)
        acc[i][j] = __builtin_amdgcn_mfma_f32_16x16x32_bf16(af[i], bf[j], acc[i][j], 0, 0, 0);

    // one barrier per K-step: all waves done reading buf[cur] (safe to
    // overwrite next iter) AND this wave's prefetch DMA drained (vmcnt 0).
    __syncthreads();
  }

#pragma unroll
  for (int i = 0; i < 4; ++i) {
    const int grow = m0 + wm * 64 + i * 16 + quad * 4;
#pragma unroll
    for (int j = 0; j < 4; ++j) {
      const int col_local = wn * 64 + j * 16 + n16;
      const int seg = n0 >> 10;                 // 0=Q 1=K 2=V (uniform, MODE 0)
      if (MODE == 0 && seg == 2) {
        // V stored transposed Vt[bh][a][s]: r=0..3 are s-consecutive -> one
        // 8B packed store (same addresses/values as 4 scalar stores).
        const int hid = (n0 & 1023) + col_local;
        const int h = hid >> 6, a = hid & 63;
        const int bi = grow >> 11, s0 = grow & 2047;
        bf16x4 v4;
#pragma unroll
        for (int r = 0; r < 4; ++r) v4[r] = (bf16)acc[i][j][r];
        *(bf16x4*)(C2 + (((size_t)bi * Hc + h) * ADc + a) * Sc + s0) = v4;
      } else {
#pragma unroll
        for (int r = 0; r < 4; ++r) {
          const int row = grow + r;
          const float v = acc[i][j][r];
          if (MODE == 1) {
            Cf[(size_t)row * Ndim + n0 + col_local] = v;   // fp32 final output
          } else {
            const int hid = (n0 & 1023) + col_local;
            const int h = hid >> 6, a = hid & 63;
            const int bi = row >> 11, s = row & 2047;
            if (seg == 0)
              // Q pre-scaled by (1/sqrt(64))*log2(e): attn computes exp2(Q.K).
              C0[(((size_t)bi * Hc + h) * Sc + s) * ADc + a] = (bf16)(v * 0.18033688011112042f);
            else
              C1[(((size_t)bi * Hc + h) * Sc + s) * ADc + a] = (bf16)v;
          }
        }
      }
    }
  }
}

// ---------------------------------------------------------------------------
// Flash attention, flat softmax (round-18 kernel, unchanged; control).
// 128 keys per barrier, DMA-staged double-buffered LDS (Ks/Vs[2][2], 64 KB),
// 16 barriers total. All math verified through R14 (passed, absmax 0.0024):
// swapped QK^T via 32x32x16 MFMA (P[query=lane&31][16 keys] in regs),
// raw-exp2 softmax (log2e folded into Q prescale), MFMA denominator
// dacc=mfma(P,ones) sharing of0's r<->query layout, PV A-frags in-register
// via cvt_pk+permlane32_swap (zero-LDS P), XCD-locality block decode
// (bh=blk&63, FETCH 41 MB confirmed), source-side XOR swizzle with linear
// DMA dest. R14 measured: 105.7 us, MfmaUtil 34.9, VALU 59, no spill.
// ---------------------------------------------------------------------------
__global__ __launch_bounds__(512, 4) void attn(
    const bf16* __restrict__ Qw,
    const bf16* __restrict__ Kw,
    const bf16* __restrict__ Vtw,
    const unsigned* __restrict__ mbits,
    bf16* __restrict__ Ow)   // == Qw (aliased)
{
  __shared__ __align__(16) bf16 Ks[2][2][64 * 64];  // [dbuf][keyhalf][key][dim]
  __shared__ __align__(16) bf16 Vs[2][2][64 * 64];  // [dbuf][keyhalf][dim][key]

  const int tid  = threadIdx.x;
  const int wave = tid >> 6, lane = tid & 63;
  const int l31  = lane & 31, hi = lane >> 5;
  const int sw   = lane & 7;                        // xor-swizzle key (row&7)
  // XCD-locality decode: blocks of one bh differ by 64 in blockIdx -> all
  // congruent mod 8 -> same XCD L2 serves that bh's K/V.
  const int bh   = blockIdx.x & 63, qb = blockIdx.x >> 6;
  const int b    = bh >> 4;
  const int q0w  = qb * 256 + wave * 32;

  // DMA source coords: lane l of wave w covers LDS chunk w*64+l, i.e.
  // row = w*8 + (l>>3); it must fetch global chunk (l&7) ^ (row&7) of that
  // row, and (row&7) == (l>>3). Element offset = chunk*8.
  const int drow = wave * 8 + (lane >> 3);
  const int dchk = ((lane & 7) ^ (lane >> 3)) * 8;
  const bf16* gK = Kw  + ((size_t)bh * Sc + drow) * ADc + dchk;  // +kt*128*ADc
  const bf16* gV = Vtw + ((size_t)bh * ADc + drow) * Sc + dchk;  // +kt*128
  const int ldsb = wave * 1024;                     // wave-uniform byte base

  // Q B-frags, resident (pre-scaled by 0.125*log2e): row = query q0w+l31,
  // MFMA k = 8*hi + j  ->  element 16*ks + 8*hi + j
  const bf16* qrow = Qw + ((size_t)bh * Sc + q0w + l31) * ADc + hi * 8;
  bfrag qf[4];
#pragma unroll
  for (int ks = 0; ks < 4; ++ks) qf[ks] = ldb(qrow + ks * 16);

  // all-ones B-frag for the denominator MFMA
  bfrag onef;
#pragma unroll
  for (int i = 0; i < 8; ++i) onef[i] = (bf16)1.0f;

  f32x16 of0  = zero16();   // O[query][dim 0..31]
  f32x16 of1  = zero16();   // O[query][dim 32..63]
  f32x16 dacc = zero16();   // denominator, same r<->query layout as of0/of1

  // one mask row per lane: its query q0w+l31; 128 key-bits per iter = uint4
  const unsigned* mq = mbits + ((size_t)b * Sc + q0w + l31) * (Sc / 32);

  // one 64-key half: QK^T (swapped) -> exp2/mask/pack -> PV + denom MFMA
  auto tile_compute = [&](const bf16* Kbuf, const bf16* Vbuf, unsigned mx,
                          unsigned my) {
#pragma unroll
    for (int nt = 0; nt < 2; ++nt) {
      // S^T subtile: D[key 32nt+..][query], key = (r&3)+8*(r>>2)+4*hi
      f32x16 sf = zero16();
#pragma unroll
      for (int ks = 0; ks < 4; ++ks) {
        const bfrag kf = ldb(Kbuf + (nt * 32 + l31) * 64 + (((2 * ks + hi) ^ sw) * 8));
        sf = __builtin_amdgcn_mfma_f32_32x32x16_bf16(kf, qf[ks], sf, 0, 0, 0);
      }

      // softmax: exp2 via raw v_exp_f32 intrinsic (log2e pre-folded into Q),
      // mask bit (r&3)+8*(r>>2) after pre-shift by 4*hi, pack to bf16 dwords
      const unsigned w = (nt ? my : mx) >> (hi * 4);
      unsigned D[8];
#pragma unroll
      for (int m = 0; m < 8; ++m) {
        const int r0 = 2 * m, r1 = r0 + 1;
        float p0 = __builtin_amdgcn_exp2f(sf[r0]);
        float p1 = __builtin_amdgcn_exp2f(sf[r1]);
        if ((w >> ((r0 & 3) + 8 * (r0 >> 2))) & 1u) p0 = 0.f;
        if ((w >> ((r1 & 3) + 8 * (r1 >> 2))) & 1u) p1 = 0.f;
        D[m] = pack2(p0, p1);
      }

      // P A-frags via permlane32_swap (keys 32nt+16a+8hi+j at elem j),
      // then PV + denominator MFMA (B = ones: D[q][*] = sum_k P[q][k])
#pragma unroll
      for (int a = 0; a < 2; ++a) {
        unsigned w0 = D[4 * a + 0], w2 = D[4 * a + 2];
        plswap(w0, w2);
        unsigned w1 = D[4 * a + 1], w3 = D[4 * a + 3];
        plswap(w1, w3);
        union { unsigned u[4]; bfrag f; } pu;
        pu.u[0] = w0; pu.u[1] = w1; pu.u[2] = w2; pu.u[3] = w3;
        const int vg = ((4 * nt + 2 * a + hi) ^ sw) * 8;
        const bfrag vf0 = ldb(Vbuf + l31 * 64 + vg);
        of0 = __builtin_amdgcn_mfma_f32_32x32x16_bf16(pu.f, vf0, of0, 0, 0, 0);
        const bfrag vf1 = ldb(Vbuf + (32 + l31) * 64 + vg);
        of1 = __builtin_amdgcn_mfma_f32_32x32x16_bf16(pu.f, vf1, of1, 0, 0, 0);
        dacc = __builtin_amdgcn_mfma_f32_32x32x16_bf16(pu.f, onef, dacc, 0, 0, 0);
      }
    }
  };

  // async-DMA stage of 128-key tile kt into dbuf buf (4 x 16B per thread)
  auto stage = [&](int buf, int kt) {
    const bf16* k0 = gK + (size_t)kt * 128 * ADc;
    const bf16* v0 = gV + (size_t)kt * 128;
    gload_lds16(k0,            (char*)Ks[buf][0] + ldsb);
    gload_lds16(k0 + 64 * ADc, (char*)Ks[buf][1] + ldsb);
    gload_lds16(v0,            (char*)Vs[buf][0] + ldsb);
    gload_lds16(v0 + 64,       (char*)Vs[buf][1] + ldsb);
  };

  // prologue: stage tile 0; __syncthreads' implicit vmcnt(0) covers the DMA
  stage(0, 0);
  __syncthreads();

  for (int kt = 0; kt < Sc / 128; ++kt) {
    const int cur = kt & 1;
    if (kt + 1 < Sc / 128) stage(cur ^ 1, kt + 1);  // async; hidden by compute

    const uint4 mwv = *(const uint4*)(mq + kt * 4);
    tile_compute(Ks[cur][0], Vs[cur][0], mwv.x, mwv.y);
    tile_compute(Ks[cur][1], Vs[cur][1], mwv.z, mwv.w);

    __syncthreads();   // drains this wave's DMA (vmcnt 0) + all waves synced
  }

  // epilogue: normalize directly -- of0[r] and dacc[r] share the same query
#pragma unroll
  for (int r = 0; r < 16; ++r) {
    const int query = (r & 3) + 8 * (r >> 2) + 4 * hi;
    const float invr = 1.f / dacc[r];
    bf16* orow = Ow + ((size_t)bh * Sc + q0w + query) * ADc + l31;
    orow[0]  = (bf16)(of0[r] * invr);
    orow[32] = (bf16)(of1[r] * invr);
  }
}

extern "C" void kernel_launch(void* const* d_in, const int* in_sizes, int n_in,
                              void* d_out, int out_size, void* d_ws, size_t ws_size,
                              hipStream_t stream) {
  const float* iQ = (const float*)d_in[0];
  const int* mask = (const int*)d_in[1];
  const float* Wa = (const float*)d_in[2];
  const float* Wo = (const float*)d_in[3];
  float* out      = (float*)d_out;   // 8.4M fp32 = 32 MB

  // d_out doubles as scratch until the final GEMM overwrites all of it:
  bf16* iQb       = (bf16*)d_out;                     // 16 MB
  bf16* Wab       = iQb + QKV_ELEMS;                  // 6 MB
  unsigned* mbits = (unsigned*)(Wab + 3145728);       // 2 MB
  // Workspace (50 MB): Q/O share a buffer; Wob read by the final GEMM.
  bf16* Qw  = (bf16*)d_ws;        // 16 MB (Q, then O)
  bf16* Kw  = Qw + QKV_ELEMS;     // 16 MB
  bf16* Vtw = Kw + QKV_ELEMS;     // 16 MB
  bf16* Wob = Vtw + QKV_ELEMS;    // 2 MB

  prep<<<dim3(8192), 256, 0, stream>>>(iQ, Wa, Wo, iQb, Wab, Wob, mask, mbits);
  gemm_bt<0><<<dim3(24, 64), 256, 0, stream>>>(iQb, Wab, Qw, Kw, Vtw, nullptr, 1024, 3072);
  attn<<<dim3(Bc * Hc * 8), 512, 0, stream>>>(Qw, Kw, Vtw, mbits, Qw);
  gemm_bt<1><<<dim3(8, 64), 256, 0, stream>>>(Qw, Wob, nullptr, nullptr, nullptr, out, 1024, 1024);
}